// Round 1
// 1471.051 us; speedup vs baseline: 1.2252x; 1.2252x over previous
//
#include <hip/hip_runtime.h>
#include <math.h>

#define NROWS 16384
#define DIMK  1024
#define MDIC  4096
#define KSEL  16

// ---- output layout (f32 elements, concatenated in reference return order) ----
#define OFF_RECON   0
#define OFF_RESID   ((size_t)NROWS*DIMK)                  // 16777216
#define OFF_CHOSEN  ((size_t)2*NROWS*DIMK)                // 33554432
#define OFF_WEIGHTS (OFF_CHOSEN + 16)                     // 33554448
#define OFF_WT      (OFF_WEIGHTS + 16)                    // 33554464
#define OFF_EVR     (OFF_WT + (size_t)NROWS*KSEL)         // 33816608
#define OFF_L2      (OFF_EVR + 16)
#define OFF_COS     (OFF_L2 + 16)

typedef unsigned short u16;
typedef unsigned long long u64;
typedef __attribute__((ext_vector_type(8))) short short8;   // 8 bf16 (4 VGPRs)
typedef __attribute__((ext_vector_type(4))) float f32x4;

// ------------------------------- helpers -------------------------------------
__device__ inline float blockReduce256f(float v) {
    __shared__ float ws_[4];
    #pragma unroll
    for (int off = 32; off > 0; off >>= 1) v += __shfl_down(v, off);
    __syncthreads();
    if ((threadIdx.x & 63) == 0) ws_[threadIdx.x >> 6] = v;
    __syncthreads();
    return ws_[0] + ws_[1] + ws_[2] + ws_[3];
}

// per-wave shuffle reduce of a double; lane0 of each wave stores to accS[k][wave]
__device__ inline void wredStore(double v, int k, int lane, int wv, double (*accS)[4]) {
    #pragma unroll
    for (int off = 32; off > 0; off >>= 1) v += __shfl_down(v, off);
    if (lane == 0) accS[k][wv] = v;
}

__device__ inline u16 f2bf(float f) {
    unsigned u = __float_as_uint(f);
    unsigned r = u + 0x7FFFu + ((u >> 16) & 1u);   // round-to-nearest-even
    return (u16)(r >> 16);
}
__device__ inline float bf2f(u16 h) { return __uint_as_float(((unsigned)h) << 16); }

// ------------------------------- kernels -------------------------------------
__global__ void k_init(float* notchosen, u64* amx, u64* statsAcc, u64* ctr2) {
    int m = blockIdx.x * 256 + threadIdx.x;
    if (m < MDIC) notchosen[m] = 1.0f;
    if (blockIdx.x == 0) {
        if (threadIdx.x < 40) statsAcc[threadIdx.x] = 0ULL;
        if (threadIdx.x < 2)  amx[threadIdx.x] = 0ULL;
        if (threadIdx.x == 0) *ctr2 = 0ULL;
    }
}

// column sums (for mean) + total sum of squares; partials, deterministic
__global__ __launch_bounds__(256) void k_colstats(const float* __restrict__ X,
                                                  float* __restrict__ colpart,
                                                  float* __restrict__ sqpart) {
    int d  = blockIdx.x * 256 + threadIdx.x;
    int r0 = blockIdx.y * 256;
    float s = 0.f, sq = 0.f;
    for (int r = 0; r < 256; ++r) {
        float v = X[(size_t)(r0 + r) * DIMK + d];
        s += v; sq += v * v;
    }
    colpart[(size_t)blockIdx.y * DIMK + d] = s;
    __shared__ float red[256];
    red[threadIdx.x] = sq; __syncthreads();
    for (int off = 128; off > 0; off >>= 1) {
        if (threadIdx.x < off) red[threadIdx.x] += red[threadIdx.x + off];
        __syncthreads();
    }
    if (threadIdx.x == 0) sqpart[blockIdx.y * 4 + blockIdx.x] = red[0];
}

// xmean[d]; scal[0]=sumX2, scal[1]=sumXc2, scal[2]=||xmean||^2
__global__ __launch_bounds__(1024) void k_reduce_mean(const float* __restrict__ colpart,
                                                      const float* __restrict__ sqpart,
                                                      float* __restrict__ xmean,
                                                      double* __restrict__ scal) {
    int d = threadIdx.x;
    double s = 0.0;
    for (int y = 0; y < 64; ++y) s += (double)colpart[(size_t)y * DIMK + d];
    float m = (float)(s / (double)NROWS);
    xmean[d] = m;
    __shared__ double red[1024];
    red[d] = (double)m * (double)m; __syncthreads();
    for (int off = 512; off > 0; off >>= 1) {
        if (d < off) red[d] += red[d + off];
        __syncthreads();
    }
    if (d == 0) {
        double xmn2 = red[0];
        double sx2 = 0.0;
        for (int i = 0; i < 256; ++i) sx2 += (double)sqpart[i];
        scal[0] = sx2;
        scal[1] = sx2 - (double)NROWS * xmn2;   // sum of squares of centered X
        scal[2] = xmn2;
    }
}

// md[m] = xmean . Dict[m]  and  Dnorm2[m] = ||Dict[m]||^2 (same tree as gram dots)
__global__ __launch_bounds__(256) void k_md(const float* __restrict__ Dict,
                                            const float* __restrict__ xmean,
                                            float* __restrict__ md,
                                            float* __restrict__ Dnorm2) {
    int m = blockIdx.x, t = threadIdx.x;
    float4 a = ((const float4*)(Dict + (size_t)m * DIMK))[t];
    float4 b = ((const float4*)xmean)[t];
    float s  = a.x * b.x + a.y * b.y + a.z * b.z + a.w * b.w;
    float sn = a.x * a.x + a.y * a.y + a.z * a.z + a.w * a.w;
    s  = blockReduce256f(s);
    sn = blockReduce256f(sn);
    if (t == 0) { md[m] = s; Dnorm2[m] = sn; }
}

// split f32 -> bf16 hi + bf16 lo planes (generic, used for Dict)
__global__ __launch_bounds__(256) void k_split(const float* __restrict__ src,
                                               u16* __restrict__ hi,
                                               u16* __restrict__ lo) {
    size_t idx = ((size_t)blockIdx.x * 256 + threadIdx.x) * 4;
    float4 v = *(const float4*)(src + idx);
    ushort4 h, l;
    h.x = f2bf(v.x); l.x = f2bf(v.x - bf2f(h.x));
    h.y = f2bf(v.y); l.y = f2bf(v.y - bf2f(h.y));
    h.z = f2bf(v.z); l.z = f2bf(v.z - bf2f(h.z));
    h.w = f2bf(v.w); l.w = f2bf(v.w - bf2f(h.w));
    *(ushort4*)(hi + idx) = h;
    *(ushort4*)(lo + idx) = l;
}

// fused: split X row -> bf16 planes  +  per-row ||X_n||^2 and X_n . xmean
__global__ __launch_bounds__(256) void k_splitX(const float* __restrict__ src,
                                                u16* __restrict__ hi,
                                                u16* __restrict__ lo,
                                                const float* __restrict__ xmean,
                                                float* __restrict__ Xnorm2,
                                                float* __restrict__ XdotM) {
    int n = blockIdx.x, t = threadIdx.x;
    size_t idx = (size_t)n * DIMK + t * 4;
    float4 v = *(const float4*)(src + idx);
    float4 mv = ((const float4*)xmean)[t];
    ushort4 h, l;
    h.x = f2bf(v.x); l.x = f2bf(v.x - bf2f(h.x));
    h.y = f2bf(v.y); l.y = f2bf(v.y - bf2f(h.y));
    h.z = f2bf(v.z); l.z = f2bf(v.z - bf2f(h.z));
    h.w = f2bf(v.w); l.w = f2bf(v.w - bf2f(h.w));
    *(ushort4*)(hi + idx) = h;
    *(ushort4*)(lo + idx) = l;
    float s2 = v.x * v.x + v.y * v.y + v.z * v.z + v.w * v.w;
    float sm = v.x * mv.x + v.y * mv.y + v.z * mv.z + v.w * mv.w;
    s2 = blockReduce256f(s2);
    sm = blockReduce256f(sm);
    if (t == 0) { Xnorm2[n] = s2; XdotM[n] = sm; }
}

// bf16x3 MFMA GEMM -> C0h[n,m] = bf16(X_n . D_m - md[m])
__global__ __launch_bounds__(256) void k_gemm_mfma(const u16* __restrict__ Ahi,
                                                   const u16* __restrict__ Alo,
                                                   const u16* __restrict__ Bhi,
                                                   const u16* __restrict__ Blo,
                                                   const float* __restrict__ md,
                                                   u16* __restrict__ C0h,
                                                   int rowAbase) {
    __shared__ u16 sAh[128 * 32];
    __shared__ u16 sAl[128 * 32];
    __shared__ u16 sBh[128 * 32];
    __shared__ u16 sBl[128 * 32];
    int tid  = threadIdx.x;
    int wave = tid >> 6, lane = tid & 63;
    int rowA0 = blockIdx.y * 128;    // within chunk
    int rowB0 = blockIdx.x * 128;

    const u16* gsrc = (wave == 0) ? Ahi : (wave == 1) ? Alo : (wave == 2) ? Bhi : Blo;
    u16* sdst       = (wave == 0) ? sAh : (wave == 1) ? sAl : (wave == 2) ? sBh : sBl;
    int grow0 = (wave < 2) ? rowA0 : rowB0;
    const u16* gbase = gsrc + (size_t)(grow0 + (lane >> 2)) * DIMK + ((lane & 3) << 3);

    f32x4 zero = {0.f, 0.f, 0.f, 0.f};
    f32x4 acc[4][4];
    #pragma unroll
    for (int i = 0; i < 4; ++i)
        #pragma unroll
        for (int j = 0; j < 4; ++j) acc[i][j] = zero;

    int lm = lane & 15, lk = lane >> 4;
    int wi = wave >> 1, wj = wave & 1;

    for (int k0 = 0; k0 < DIMK; k0 += 32) {
        __syncthreads();
        #pragma unroll
        for (int i = 0; i < 8; ++i) {
            __builtin_amdgcn_global_load_lds(
                (__attribute__((address_space(1))) void*)(gbase + k0 + (size_t)i * 16 * DIMK),
                (__attribute__((address_space(3))) void*)(sdst + i * 512),
                16, 0, 0);
        }
        __syncthreads();
        short8 ah[4], al[4], bh[4], bl[4];
        #pragma unroll
        for (int f = 0; f < 4; ++f) {
            int ra = (wi * 64 + f * 16 + lm) * 32 + lk * 8;
            ah[f] = *(const short8*)&sAh[ra];
            al[f] = *(const short8*)&sAl[ra];
            int rb = (wj * 64 + f * 16 + lm) * 32 + lk * 8;
            bh[f] = *(const short8*)&sBh[rb];
            bl[f] = *(const short8*)&sBl[rb];
        }
        #pragma unroll
        for (int fi = 0; fi < 4; ++fi)
            #pragma unroll
            for (int fj = 0; fj < 4; ++fj) {
                acc[fi][fj] = __builtin_amdgcn_mfma_f32_16x16x32_bf16(ah[fi], bh[fj], acc[fi][fj], 0, 0, 0);
                acc[fi][fj] = __builtin_amdgcn_mfma_f32_16x16x32_bf16(ah[fi], bl[fj], acc[fi][fj], 0, 0, 0);
                acc[fi][fj] = __builtin_amdgcn_mfma_f32_16x16x32_bf16(al[fi], bh[fj], acc[fi][fj], 0, 0, 0);
            }
    }
    // C/D layout: col = lane&15 -> m, row = (lane>>4)*4 + reg -> n
    #pragma unroll
    for (int fj = 0; fj < 4; ++fj) {
        int m = rowB0 + wj * 64 + fj * 16 + lm;
        float mdv = md[m];
        #pragma unroll
        for (int fi = 0; fi < 4; ++fi) {
            int nb = rowAbase + rowA0 + wi * 64 + fi * 16 + lk * 4;
            #pragma unroll
            for (int r = 0; r < 4; ++r)
                C0h[(size_t)(nb + r) * MDIC + m] = f2bf(acc[fi][fj][r] - mdv);
        }
    }
}

// score partials: sum_n |C0h[n,m] - sum_j W[j,n]*GR[j,m]| over 64-row chunk
// grid (4, 256), block 256; thread owns 4 consecutive m
template <int NA>
__global__ __launch_bounds__(256) void k_score(const u16* __restrict__ C0h,
                                               const float* __restrict__ GR,
                                               const float* __restrict__ Wm,
                                               float* __restrict__ scorePf) {
    constexpr int NAX = NA ? NA : 1;
    __shared__ float Wl[NAX][64];
    int t = threadIdx.x;
    int m0 = blockIdx.x * 1024 + t * 4;
    int n0 = blockIdx.y * 64;
    float4 gr[NAX];
    #pragma unroll
    for (int j = 0; j < NA; ++j) gr[j] = *(const float4*)&GR[(size_t)j * MDIC + m0];
    for (int idx = t; idx < NA * 64; idx += 256) {
        int j = idx >> 6, nn = idx & 63;
        Wl[j][nn] = Wm[(size_t)j * NROWS + n0 + nn];
    }
    __syncthreads();
    float4 acc = {0.f, 0.f, 0.f, 0.f};
    for (int nn = 0; nn < 64; ++nn) {
        ushort4 ch = *(const ushort4*)&C0h[(size_t)(n0 + nn) * MDIC + m0];
        float4 c = {bf2f(ch.x), bf2f(ch.y), bf2f(ch.z), bf2f(ch.w)};
        float4 cr = {0.f, 0.f, 0.f, 0.f};
        #pragma unroll
        for (int j = 0; j < NA; ++j) {
            float wv = Wl[j][nn];
            cr.x += wv * gr[j].x; cr.y += wv * gr[j].y;
            cr.z += wv * gr[j].z; cr.w += wv * gr[j].w;
        }
        acc.x += fabsf(c.x - cr.x); acc.y += fabsf(c.y - cr.y);
        acc.z += fabsf(c.z - cr.z); acc.w += fabsf(c.w - cr.w);
    }
    *(float4*)&scorePf[(size_t)blockIdx.y * MDIC + m0] = acc;
}

// fused: reduce partials -> masked argmax -> (last block) select atom, update
// notchosen/chosen, gather md/Dnorm2, and INCREMENTAL Cholesky row update.
// G[iter][b] = GR[b][c] (prior rows at new column; bitwise == old gather by
// commutativity of the dot tree), G[iter][iter] = Dnorm2[c].
__global__ __launch_bounds__(256) void k_scoreargmax(const float* __restrict__ scorePf,
                                                     float* __restrict__ notchosen,
                                                     u64* __restrict__ amx,   // [0]=key,[1]=ctr
                                                     int* __restrict__ chosen,
                                                     float* __restrict__ outChosen,
                                                     const float* __restrict__ md,
                                                     const float* __restrict__ Dnorm2,
                                                     const float* __restrict__ GR,
                                                     float* __restrict__ Lmat,
                                                     float* __restrict__ Gcc,
                                                     float* __restrict__ mdot,
                                                     int iter) {
    int t = threadIdx.x;
    int m0 = blockIdx.x * 256;          // 16 blocks x 256 m
    int tm = t & 63, yg = t >> 6;
    float sx = 0.f, sy = 0.f, sz = 0.f, sw = 0.f;
    #pragma unroll 4
    for (int y = yg; y < 256; y += 4) {
        float4 v = *(const float4*)&scorePf[(size_t)y * MDIC + m0 + (tm << 2)];
        sx += v.x; sy += v.y; sz += v.z; sw += v.w;
    }
    __shared__ float4 red4[4][64];
    float4 pv; pv.x = sx; pv.y = sy; pv.z = sz; pv.w = sw;
    red4[yg][tm] = pv;
    __syncthreads();
    u64 best = 0ULL;
    if (t < 64) {                        // wave 0 only
        float4 a = red4[0][t], b = red4[1][t], cc = red4[2][t], d = red4[3][t];
        double sv[4] = {(double)a.x + b.x + cc.x + d.x,
                        (double)a.y + b.y + cc.y + d.y,
                        (double)a.z + b.z + cc.z + d.z,
                        (double)a.w + b.w + cc.w + d.w};
        int mb = m0 + (t << 2);
        #pragma unroll
        for (int j = 0; j < 4; ++j) {
            if (notchosen[mb + j] != 0.f) {
                u64 key = ((u64)__double_as_longlong(sv[j]) & ~0xFFFULL) | (u64)(4095 - (mb + j));
                if (key > best) best = key;
            }
        }
        #pragma unroll
        for (int off = 32; off > 0; off >>= 1) {
            u64 o = __shfl_down(best, off);
            if (o > best) best = o;
        }
    }
    __shared__ int slast, sc;
    if (t == 0) {
        atomicMax(&amx[0], best);
        __threadfence();
        u64 done = atomicAdd(&amx[1], 1ULL);
        slast = (done == 15ULL) ? 1 : 0;
        if (slast) {
            u64 k = atomicMax(&amx[0], 0ULL);        // atomic read
            int c = 4095 - (int)(k & 0xFFFULL);
            sc = c;
            chosen[iter] = c;
            notchosen[c] = 0.f;
            outChosen[iter] = (float)c;
            mdot[iter] = md[c];
            amx[0] = 0ULL; amx[1] = 0ULL;            // reset for next iteration
        }
    }
    __syncthreads();
    if (!slast) return;
    // ---- incremental Cholesky row (last block only) ----
    int c = sc;
    __shared__ float Lsh[16][16];
    __shared__ float g[17];
    __shared__ float LrowS[16];
    Lsh[t >> 4][t & 15] = Lmat[t];       // rows >= iter are garbage, unused
    if (t < iter)  g[t] = GR[(size_t)t * MDIC + c];
    if (t == iter) g[t] = Dnorm2[c];
    __syncthreads();
    if (t == 0) {
        for (int b = 0; b < iter; ++b) {
            float s = g[b];
            for (int x = 0; x < b; ++x) s -= LrowS[x] * Lsh[b][x];
            LrowS[b] = s / Lsh[b][b];
        }
        float s2 = g[iter];
        for (int x = 0; x < iter; ++x) s2 -= LrowS[x] * LrowS[x];
        LrowS[iter] = sqrtf(fmaxf(s2, 1e-20f));
        for (int b = 0; b <= iter; ++b) Lmat[iter * 16 + b] = LrowS[b];
        for (int b = iter + 1; b < 16; ++b) Lmat[iter * 16 + b] = 0.f;
        for (int b = 0; b < iter; ++b) { Gcc[iter * 16 + b] = g[b]; Gcc[b * 16 + iter] = g[b]; }
        Gcc[iter * 16 + iter] = g[iter];
    }
}

// merged: blocks [0,64)  = per-row solve + stats + fused finalize (last block)
//         blocks [64, 64+MDIC) = GR[iter][m] = atom_c . D_m (exact fp32)
// stats combined via deterministic fixed-point (2^-20) u64 atomics.
template <int NAT>
__global__ __launch_bounds__(256) void k_gramsolve(const float* __restrict__ Dict,
                                                   const int* __restrict__ chosen,
                                                   const u16* __restrict__ C0h,
                                                   float* __restrict__ GR,
                                                   float* __restrict__ Bm,
                                                   const float* __restrict__ Lmat,
                                                   const float* __restrict__ Gcc_g,
                                                   const float* __restrict__ mdot,
                                                   const float* __restrict__ Xnorm2,
                                                   const float* __restrict__ XdotM,
                                                   const double* __restrict__ scal,
                                                   float* __restrict__ Wm,
                                                   u64* __restrict__ statsAcc,
                                                   u64* __restrict__ ctr2,
                                                   float* __restrict__ out, int iter) {
    int t = threadIdx.x;
    int c = chosen[iter];
    if (blockIdx.x >= 64) {
        int m = blockIdx.x - 64;
        float4 a = ((const float4*)(Dict + (size_t)c * DIMK))[t];
        float4 b = ((const float4*)(Dict + (size_t)m * DIMK))[t];
        float s = a.x * b.x + a.y * b.y + a.z * b.z + a.w * b.w;
        s = blockReduce256f(s);
        if (t == 0) GR[(size_t)iter * MDIC + m] = s;
        return;
    }
    constexpr int NV = 3 + 2 * NAT;      // q, wb, cos, ws[NAT], wq[NAT]
    __shared__ float L[16][16];
    __shared__ float G[16][16];
    __shared__ float mdl[16];
    __shared__ double accS[35][4];
    if (t < NAT * NAT) {
        int a = t / NAT, b2 = t % NAT;
        L[a][b2] = Lmat[a * 16 + b2];
        G[a][b2] = Gcc_g[a * 16 + b2];
    }
    if (t < NAT) mdl[t] = mdot[t];
    __syncthreads();
    int n = blockIdx.x * 256 + t;
    float b[NAT], y[NAT], w[NAT];
    #pragma unroll
    for (int j = 0; j < NAT - 1; ++j) b[j] = Bm[(size_t)j * NROWS + n];
    float bn = bf2f(C0h[(size_t)n * MDIC + c]);  // new RHS column, gathered in place
    b[NAT - 1] = bn;
    Bm[(size_t)(NAT - 1) * NROWS + n] = bn;
    #pragma unroll
    for (int a = 0; a < NAT; ++a) {
        float s = b[a];
        #pragma unroll
        for (int x = 0; x < NAT; ++x) if (x < a) s -= L[a][x] * y[x];
        y[a] = s / L[a][a];
    }
    #pragma unroll
    for (int a = NAT - 1; a >= 0; --a) {
        float s = y[a];
        #pragma unroll
        for (int x = 0; x < NAT; ++x) if (x > a) s -= L[x][a] * w[x];
        w[a] = s / L[a][a];
    }
    #pragma unroll
    for (int j = 0; j < NAT; ++j) Wm[(size_t)j * NROWS + n] = w[j];

    float q = 0.f, wb = 0.f, wmd = 0.f, num1 = 0.f;
    #pragma unroll
    for (int j = 0; j < NAT; ++j) {
        float gw = 0.f;
        #pragma unroll
        for (int x = 0; x < NAT; ++x) gw += G[j][x] * w[x];
        q    += w[j] * gw;
        wb   += w[j] * b[j];
        wmd  += w[j] * mdl[j];
        num1 += w[j] * (b[j] + mdl[j]);
    }
    float xmn2 = (float)scal[2];
    float rec2 = xmn2 + 2.f * wmd + q;
    float na = fmaxf(sqrtf(Xnorm2[n]), 1e-8f);
    float nb = fmaxf(sqrtf(fmaxf(rec2, 0.f)), 1e-8f);
    float cosn = (XdotM[n] + num1) / (na * nb);

    // packed reductions: per-wave shuffle chains, ONE barrier (was 70)
    int lane = t & 63, wv = t >> 6;
    wredStore((double)q,    0, lane, wv, accS);
    wredStore((double)wb,   1, lane, wv, accS);
    wredStore((double)cosn, 2, lane, wv, accS);
    #pragma unroll
    for (int j = 0; j < NAT; ++j) {
        wredStore((double)w[j],                 3 + j,       lane, wv, accS);
        wredStore((double)w[j] * (double)w[j],  3 + NAT + j, lane, wv, accS);
    }
    __syncthreads();
    if (t < NV) {
        double tot = accS[t][0] + accS[t][1] + accS[t][2] + accS[t][3];
        long long fx = (long long)(tot * 1048576.0);    // fixed-point 2^-20, deterministic
        atomicAdd(&statsAcc[t], (u64)fx);
    }
    __shared__ int slast2;
    __syncthreads();                 // drains atomics (waitcnt before barrier)
    if (t == 0) {
        __threadfence();
        slast2 = (atomicAdd(ctr2, 1ULL) == 63ULL) ? 1 : 0;
    }
    __syncthreads();
    if (!slast2) return;
    // ---- fused finalize (last solve block) ----
    __shared__ double stot[35];
    __shared__ double wbarS[16];
    if (t < NV) {
        u64 raw = atomicAdd(&statsAcc[t], 0ULL);        // coherent read
        stot[t] = (double)(long long)raw * (1.0 / 1048576.0);
        statsAcc[t] = 0ULL;                              // reset for next iteration
    }
    if (t == 0) *ctr2 = 0ULL;
    __syncthreads();
    if (t < NAT) wbarS[t] = stot[3 + t] * (1.0 / (double)NROWS);
    __syncthreads();
    if (t == 0) {
        double q2 = stot[0], wb2 = stot[1], cs = stot[2];
        double wg = 0.0;
        for (int a = 0; a < NAT; ++a)
            for (int b2 = 0; b2 < NAT; ++b2) wg += wbarS[a] * wbarS[b2] * (double)G[a][b2];
        double sumXc2 = scal[1];
        out[OFF_EVR + iter] = (float)((q2 - (double)NROWS * wg) / sumXc2);
        out[OFF_L2  + iter] = (float)((sumXc2 - 2.0 * wb2 + q2) / ((double)NROWS * (double)DIMK));
        out[OFF_COS + iter] = (float)(cs / (double)NROWS);
        if (NAT == KSEL) {
            for (int j = 0; j < NAT; ++j)
                out[OFF_WEIGHTS + j] = (float)sqrt(stot[3 + NAT + j]);
        }
    }
}

// final recon / residual outputs (+ W.T folded in)
__global__ __launch_bounds__(256) void k_outfinal(const float* __restrict__ X,
                                                  const float* __restrict__ xmean,
                                                  const float* __restrict__ Dict,
                                                  const int* __restrict__ chosen,
                                                  const float* __restrict__ Wm,
                                                  float* __restrict__ out) {
    __shared__ int cI[16];
    int t = threadIdx.x;
    if (t < 16) cI[t] = chosen[t];
    __syncthreads();
    int n0 = blockIdx.x * 8;
    if (t < 128) {                       // W.T output: 8 rows x 16
        int j = t & 15, r = t >> 4;
        int n = n0 + r;
        out[OFF_WT + (size_t)n * 16 + j] = Wm[(size_t)j * NROWS + n];
    }
    float4 xm = ((const float4*)xmean)[t];
    for (int r = 0; r < 8; ++r) {
        int n = n0 + r;
        float w[16];
        #pragma unroll
        for (int j = 0; j < 16; ++j) w[j] = Wm[(size_t)j * NROWS + n];
        float4 rec = xm;
        #pragma unroll
        for (int j = 0; j < 16; ++j) {
            float4 a = ((const float4*)(Dict + (size_t)cI[j] * DIMK))[t];
            rec.x += w[j] * a.x; rec.y += w[j] * a.y;
            rec.z += w[j] * a.z; rec.w += w[j] * a.w;
        }
        float4 xv = ((const float4*)(X + (size_t)n * DIMK))[t];
        float4 res = {xv.x - rec.x, xv.y - rec.y, xv.z - rec.z, xv.w - rec.w};
        ((float4*)(out + OFF_RECON + (size_t)n * DIMK))[t] = rec;
        ((float4*)(out + OFF_RESID + (size_t)n * DIMK))[t] = res;
    }
}

// ------------------------------ host side ------------------------------------
struct IterArgs {
    const float *X, *Dict;
    u16 *C0h;
    float *GR, *W, *Bm, *md, *Dnorm2, *xmean, *Xnorm2, *XdotM, *notchosen, *Lmat, *Gcc, *mdot;
    float *scorePf;
    u64 *amx, *statsAcc, *ctr2;
    double *scal;
    int *chosen;
    float *out;
    hipStream_t stream;
};

template <int I>
static void run_iter(const IterArgs& a) {
    k_score<I><<<dim3(4, 256), 256, 0, a.stream>>>(a.C0h, a.GR, a.W, a.scorePf);
    k_scoreargmax<<<16, 256, 0, a.stream>>>(a.scorePf, a.notchosen, a.amx, a.chosen,
                                            a.out + OFF_CHOSEN, a.md, a.Dnorm2, a.GR,
                                            a.Lmat, a.Gcc, a.mdot, I);
    k_gramsolve<I + 1><<<MDIC + 64, 256, 0, a.stream>>>(a.Dict, a.chosen, a.C0h, a.GR,
                                                        a.Bm, a.Lmat, a.Gcc, a.mdot,
                                                        a.Xnorm2, a.XdotM, a.scal, a.W,
                                                        a.statsAcc, a.ctr2, a.out, I);
}

template <int I>
struct Loop {
    static void go(const IterArgs& a) { run_iter<I>(a); Loop<I + 1>::go(a); }
};
template <>
struct Loop<KSEL> { static void go(const IterArgs&) {} };

extern "C" void kernel_launch(void* const* d_in, const int* in_sizes, int n_in,
                              void* d_out, int out_size, void* d_ws, size_t ws_size,
                              hipStream_t stream) {
    (void)in_sizes; (void)n_in; (void)out_size;
    const float* X    = (const float*)d_in[0];
    const float* Dict = (const float*)d_in[1];
    float* out = (float*)d_out;

    char* ws = (char*)d_ws;
    size_t off = 0;
    auto carve = [&](size_t bytes) -> char* {
        char* p = ws + off;
        off += (bytes + 255) & ~(size_t)255;
        return p;
    };
    u16*    C0h       = (u16*)   carve((size_t)NROWS * MDIC * 2);   // 134 MB
    float*  GR        = (float*) carve((size_t)KSEL * MDIC * 4);
    float*  W         = (float*) carve((size_t)KSEL * NROWS * 4);
    float*  Bm        = (float*) carve((size_t)KSEL * NROWS * 4);
    float*  md        = (float*) carve((size_t)MDIC * 4);
    float*  Dnorm2    = (float*) carve((size_t)MDIC * 4);
    float*  xmean     = (float*) carve((size_t)DIMK * 4);
    float*  colpart   = (float*) carve((size_t)64 * DIMK * 4);
    float*  sqpart    = (float*) carve(256 * 4);
    float*  Xnorm2    = (float*) carve((size_t)NROWS * 4);
    float*  XdotM     = (float*) carve((size_t)NROWS * 4);
    float*  scorePf   = (float*) carve((size_t)256 * MDIC * 4);     // 4 MB
    float*  notchosen = (float*) carve((size_t)MDIC * 4);
    u64*    amx       = (u64*)   carve(2 * 8);
    u64*    statsAcc  = (u64*)   carve(40 * 8);
    u64*    ctr2      = (u64*)   carve(8);
    int*    chosen    = (int*)   carve(KSEL * 4);
    float*  Lmat      = (float*) carve(256 * 4);
    float*  Gcc       = (float*) carve(256 * 4);
    float*  mdot      = (float*) carve(16 * 4);
    double* scal      = (double*)carve(8 * 8);
    u16*    Bhi       = (u16*)   carve((size_t)MDIC * DIMK * 2);    // 8 MB
    u16*    Blo       = (u16*)   carve((size_t)MDIC * DIMK * 2);    // 8 MB

    // A-plane chunk buffers take the tail of ws; pick largest chunk that fits.
    int chunkrows = 0;
    for (int cr = NROWS; cr >= 128; cr >>= 1) {
        size_t need = (size_t)cr * DIMK * 2 * 2 + 512;
        if (off + need <= ws_size) { chunkrows = cr; break; }
    }
    if (chunkrows == 0) chunkrows = 128;
    u16* Ahi = (u16*) carve((size_t)chunkrows * DIMK * 2);
    u16* Alo = (u16*) carve((size_t)chunkrows * DIMK * 2);

    k_init<<<MDIC / 256, 256, 0, stream>>>(notchosen, amx, statsAcc, ctr2);
    k_colstats<<<dim3(4, 64), 256, 0, stream>>>(X, colpart, sqpart);
    k_reduce_mean<<<1, 1024, 0, stream>>>(colpart, sqpart, xmean, scal);
    k_md<<<MDIC, 256, 0, stream>>>(Dict, xmean, md, Dnorm2);

    // bf16 hi/lo planes + chunked MFMA GEMM (X split fused with row stats)
    k_split<<<(MDIC * DIMK) / 1024, 256, 0, stream>>>(Dict, Bhi, Blo);
    int nchunks = NROWS / chunkrows;
    for (int c = 0; c < nchunks; ++c) {
        k_splitX<<<chunkrows, 256, 0, stream>>>(
            X + (size_t)c * chunkrows * DIMK, Ahi, Alo, xmean,
            Xnorm2 + (size_t)c * chunkrows, XdotM + (size_t)c * chunkrows);
        k_gemm_mfma<<<dim3(MDIC / 128, chunkrows / 128), 256, 0, stream>>>(
            Ahi, Alo, Bhi, Blo, md, C0h, c * chunkrows);
    }

    IterArgs a{X, Dict, C0h, GR, W, Bm, md, Dnorm2, xmean, Xnorm2, XdotM, notchosen,
               Lmat, Gcc, mdot, scorePf, amx, statsAcc, ctr2, scal, chosen, out, stream};
    Loop<0>::go(a);

    k_outfinal<<<NROWS / 8, 256, 0, stream>>>(X, xmean, Dict, chosen, W, out);
}